// Round 2
// baseline (129.266 us; speedup 1.0000x reference)
//
#include <hip/hip_runtime.h>

// ---------------------------------------------------------------------------
// Kernel 1: per-Gaussian preprocessing. Writes areas, unsorted param SoA,
// depth sort keys, zero-inits rank (rank doubles as arrival-packed slot acc).
// ---------------------------------------------------------------------------
__global__ __launch_bounds__(256) void k_pre(
    const float* __restrict__ pws, const float* __restrict__ shs,
    const float* __restrict__ alphas_raw, const float* __restrict__ scales_raw,
    const float* __restrict__ rots_raw, const float* __restrict__ Rcw,
    const float* __restrict__ tcw, const float* __restrict__ intr,
    int N, int W, int H, float* __restrict__ areas,
    unsigned long long* __restrict__ keys, unsigned* __restrict__ rank,
    float* __restrict__ P)
{
    int i = blockIdx.x * 256 + threadIdx.x;
    if (i >= N) return;
    rank[i] = 0u;

    float R00=Rcw[0],R01=Rcw[1],R02=Rcw[2];
    float R10=Rcw[3],R11=Rcw[4],R12=Rcw[5];
    float R20=Rcw[6],R21=Rcw[7],R22=Rcw[8];
    float t0=tcw[0],t1=tcw[1],t2=tcw[2];
    float fx=intr[0],fy=intr[1],cx=intr[2],cy=intr[3];

    float pwx=pws[i*3+0], pwy=pws[i*3+1], pwz=pws[i*3+2];
    float pcx = R00*pwx + R01*pwy + R02*pwz + t0;
    float pcy = R10*pwx + R11*pwy + R12*pwz + t1;
    float pcz = R20*pwx + R21*pwy + R22*pwz + t2;
    float depth = pcz;
    float zs = (depth > 0.2f) ? depth : 1.0f;
    float u0 = fx * pcx / zs + cx;
    float u1 = fy * pcy / zs + cy;

    float qw=rots_raw[i*4+0], qx=rots_raw[i*4+1], qy=rots_raw[i*4+2], qz=rots_raw[i*4+3];
    float qn = sqrtf(qw*qw + qx*qx + qy*qy + qz*qz);
    qw/=qn; qx/=qn; qy/=qn; qz/=qn;
    float s0 = expf(scales_raw[i*3+0]);
    float s1 = expf(scales_raw[i*3+1]);
    float s2 = expf(scales_raw[i*3+2]);

    float xx=qx*qx, yy=qy*qy, zq=qz*qz;
    float xy=qx*qy, xz=qx*qz, yz=qy*qz;
    float wx=qw*qx, wy=qw*qy, wz=qw*qz;
    float r00=1.f-2.f*(yy+zq), r01=2.f*(xy-wz),     r02=2.f*(xz+wy);
    float r10=2.f*(xy+wz),     r11=1.f-2.f*(xx+zq), r12=2.f*(yz-wx);
    float r20=2.f*(xz-wy),     r21=2.f*(yz+wx),     r22=1.f-2.f*(xx+yy);

    float m00=r00*s0, m01=r01*s1, m02=r02*s2;
    float m10=r10*s0, m11=r11*s1, m12=r12*s2;
    float m20=r20*s0, m21=r21*s1, m22=r22*s2;
    float V00=m00*m00+m01*m01+m02*m02;
    float V01=m00*m10+m01*m11+m02*m12;
    float V02=m00*m20+m01*m21+m02*m22;
    float V11=m10*m10+m11*m11+m12*m12;
    float V12=m10*m20+m11*m21+m12*m22;
    float V22=m20*m20+m21*m21+m22*m22;

    float tanfx = (float)W / (2.f*fx), tanfy = (float)H / (2.f*fy);
    float limx = 1.3f*tanfx, limy = 1.3f*tanfy;
    float txl = fminf(fmaxf(pcx/zs, -limx), limx) * zs;
    float tyl = fminf(fmaxf(pcy/zs, -limy), limy) * zs;
    float iz = 1.f/zs, iz2 = iz*iz;
    float J00 = fx*iz, J02 = -fx*txl*iz2;
    float J11 = fy*iz, J12 = -fy*tyl*iz2;

    float T00=J00*R00+J02*R20, T01=J00*R01+J02*R21, T02=J00*R02+J02*R22;
    float T10=J11*R10+J12*R20, T11=J11*R11+J12*R21, T12=J11*R12+J12*R22;
    float A0=T00*V00+T01*V01+T02*V02;
    float A1=T00*V01+T01*V11+T02*V12;
    float A2=T00*V02+T01*V12+T02*V22;
    float B0=T10*V00+T11*V01+T12*V02;
    float B1=T10*V01+T11*V11+T12*V12;
    float B2=T10*V02+T11*V12+T12*V22;
    float ca = A0*T00+A1*T01+A2*T02 + 0.3f;
    float cb = A0*T10+A1*T11+A2*T12;
    float cc = B0*T10+B1*T11+B2*T12 + 0.3f;

    float det = ca*cc - cb*cb;
    bool valid = (depth > 0.2f) && (det > 0.f);
    float det_s = valid ? det : 1.f;
    float dinv = 1.f/det_s;
    float ci0 =  cc*dinv, ci1 = -cb*dinv, ci2 = ca*dinv;
    float mid = 0.5f*(ca+cc);
    float lam = mid + sqrtf(fmaxf(mid*mid - det, 0.1f));
    float radius = valid ? ceilf(3.f*sqrtf(lam)) : 0.f;
    areas[2*i+0] = radius;
    areas[2*i+1] = radius;

    float alpha = 1.f/(1.f + expf(-alphas_raw[i]));

    float tw0 = -(R00*t0 + R10*t1 + R20*t2);
    float tw1 = -(R01*t0 + R11*t1 + R21*t2);
    float tw2 = -(R02*t0 + R12*t1 + R22*t2);
    float dx_=pwx-tw0, dy_=pwy-tw1, dz_=pwz-tw2;
    float dn = sqrtf(dx_*dx_+dy_*dy_+dz_*dz_);
    float x=dx_/dn, y=dy_/dn, z=dz_/dn;
    float sxx=x*x, syy=y*y, szz=z*z;
    float sxy=x*y, syz=y*z, sxz=x*z;
    const float* sh = shs + i*48;
    float col[3];
    #pragma unroll
    for (int c = 0; c < 3; ++c) {
        float res = 0.28209479177387814f*sh[0*3+c];
        res += -0.4886025119029199f*y*sh[1*3+c]
             +  0.4886025119029199f*z*sh[2*3+c]
             + -0.4886025119029199f*x*sh[3*3+c];
        res +=  1.0925484305920792f*sxy*sh[4*3+c]
             + -1.0925484305920792f*syz*sh[5*3+c]
             +  0.31539156525252005f*(2.f*szz-sxx-syy)*sh[6*3+c]
             + -1.0925484305920792f*sxz*sh[7*3+c]
             +  0.5462742152960396f*(sxx-syy)*sh[8*3+c];
        res += -0.5900435899266435f*y*(3.f*sxx-syy)*sh[9*3+c]
             +  2.890611442640554f*sxy*z*sh[10*3+c]
             + -0.4570457994644658f*y*(4.f*szz-sxx-syy)*sh[11*3+c]
             +  0.3731763325901154f*z*(2.f*szz-3.f*sxx-3.f*syy)*sh[12*3+c]
             + -0.4570457994644658f*x*(4.f*szz-sxx-syy)*sh[13*3+c]
             +  1.445305721320277f*z*(sxx-syy)*sh[14*3+c]
             + -0.5900435899266435f*x*(sxx-3.f*syy)*sh[15*3+c];
        col[c] = fmaxf(res + 0.5f, 0.f);
    }

    float rc2;
    if (!valid || 255.f*alpha < 0.999f) {
        rc2 = -1.f;
    } else {
        float r2 = 2.f*lam*logf(255.f*alpha);
        float r  = sqrtf(fmaxf(r2, 0.f)) + 1.f;
        rc2 = r*r;
    }

    P[0*N+i]=u0;  P[1*N+i]=u1;  P[2*N+i]=ci0; P[3*N+i]=ci1; P[4*N+i]=ci2;
    P[5*N+i]=alpha; P[6*N+i]=col[0]; P[7*N+i]=col[1]; P[8*N+i]=col[2];
    P[9*N+i]=rc2;

    unsigned ud = __float_as_uint(depth);
    ud = (ud & 0x80000000u) ? ~ud : (ud | 0x80000000u);
    keys[i] = ((unsigned long long)ud << 32) | (unsigned)i;
}

// ---------------------------------------------------------------------------
// Kernel 2: O(N^2) rank sort fused with scatter. rank[i] accumulates
// (count | arrivals<<20) from the nJ j-tile blocks via one atomicAdd each
// (device-scope, G12). The block making the LAST arrival for i knows the
// final rank = (old & 0xFFFFF) + c and scatters i's packed params into
// sorted order inline:
//   cull[s] = (u0,u1,rc2,0); gA[s] = (ci0,ci1,ci2,alpha); gB[s] = (r,g,b,0)
// Fields can't interact: rank <= N-1 = 8191 < 2^20; arrivals <= 16.
// ---------------------------------------------------------------------------
#define JC 512
__global__ __launch_bounds__(256) void k_rank_scatter(
    const unsigned long long* __restrict__ keys, int N,
    unsigned* __restrict__ rank, const float* __restrict__ Pun,
    float4* __restrict__ gA, float4* __restrict__ gB,
    float4* __restrict__ cull)
{
    __shared__ unsigned long long sk[JC];
    const int j0 = blockIdx.y * JC;
    const int nJ = gridDim.y;
    for (int t = threadIdx.x; t < JC; t += 256) {
        int j = j0 + t;
        sk[t] = (j < N) ? keys[j] : ~0ull;
    }
    __syncthreads();

    const int i0 = blockIdx.x * 512 + threadIdx.x;
    const int i1 = i0 + 256;
    unsigned long long my0 = (i0 < N) ? keys[i0] : 0ull;
    unsigned long long my1 = (i1 < N) ? keys[i1] : 0ull;

    int c0 = 0, c1 = 0;
    const ulonglong2* sk2 = (const ulonglong2*)sk;
    #pragma unroll 4
    for (int t = 0; t < JC/2; ++t) {
        ulonglong2 kk = sk2[t];
        c0 += (kk.x < my0) ? 1 : 0;
        c0 += (kk.y < my0) ? 1 : 0;
        c1 += (kk.x < my1) ? 1 : 0;
        c1 += (kk.y < my1) ? 1 : 0;
    }
    if (i0 < N) {
        unsigned old = atomicAdd(&rank[i0], (unsigned)c0 + (1u << 20));
        if ((int)(old >> 20) == nJ - 1) {
            int s = (int)(old & 0xFFFFFu) + c0;
            cull[s] = make_float4(Pun[0*N+i0], Pun[1*N+i0], Pun[9*N+i0], 0.f);
            gA[s]   = make_float4(Pun[2*N+i0], Pun[3*N+i0], Pun[4*N+i0], Pun[5*N+i0]);
            gB[s]   = make_float4(Pun[6*N+i0], Pun[7*N+i0], Pun[8*N+i0], 0.f);
        }
    }
    if (i1 < N) {
        unsigned old = atomicAdd(&rank[i1], (unsigned)c1 + (1u << 20));
        if ((int)(old >> 20) == nJ - 1) {
            int s = (int)(old & 0xFFFFFu) + c1;
            cull[s] = make_float4(Pun[0*N+i1], Pun[1*N+i1], Pun[9*N+i1], 0.f);
            gA[s]   = make_float4(Pun[2*N+i1], Pun[3*N+i1], Pun[4*N+i1], Pun[5*N+i1]);
            gB[s]   = make_float4(Pun[6*N+i1], Pun[7*N+i1], Pun[8*N+i1], 0.f);
        }
    }
}

// ---------------------------------------------------------------------------
// Kernel 3: single-segment tile render, writes image planes directly.
// nseg=1 == exact reference semantics (global T, Ti>1e-4 cutoff). Front-to-
// back depth order + early exit: block stops as soon as every pixel's T
// drops below 1e-4 (typically after 1-2 chunks given mean alpha ~0.5).
// ---------------------------------------------------------------------------
__global__ __launch_bounds__(256) void k_render(
    const float4* __restrict__ gA, const float4* __restrict__ gB,
    const float4* __restrict__ cull, int N, int W, int H,
    float* __restrict__ out)
{
    const int tid = threadIdx.x;
    const int tilesX = (W + 15) >> 4;
    const int tile = blockIdx.x;
    const int tX = tile % tilesX, tY = tile / tilesX;
    const int ix = (tX << 4) + (tid & 15);
    const int iy = (tY << 4) + (tid >> 4);
    const bool inb = (ix < W) && (iy < H);
    const float pxf = (float)ix, pyf = (float)iy;
    const float tx0 = (float)(tX << 4), ty0 = (float)(tY << 4);
    int tx1i = (tX << 4) + 15; if (tx1i > W-1) tx1i = W-1;
    int ty1i = (tY << 4) + 15; if (ty1i > H-1) ty1i = H-1;
    const float tx1 = (float)tx1i, ty1 = (float)ty1i;

    float T = inb ? 1.f : 0.f;
    float aR = 0.f, aG = 0.f, aB = 0.f;

    __shared__ float4 sG0[256];   // u0,u1,ci0,ci1
    __shared__ float4 sG1[256];   // ci2,alpha,r,g
    __shared__ float  sB2[256];   // b
    __shared__ unsigned long long sMask[4];

    const int wave = tid >> 6, lane = tid & 63;

    for (int base = 0; base < N; base += 256) {
        int g = base + tid;
        bool ov = false;
        float u0=0.f, u1=0.f;
        float4 a4 = make_float4(0.f,0.f,0.f,0.f);
        float4 b4 = make_float4(0.f,0.f,0.f,0.f);
        if (g < N) {
            float4 cu = cull[g];
            u0 = cu.x; u1 = cu.y;
            float cxp = fminf(fmaxf(u0, tx0), tx1);
            float cyp = fminf(fmaxf(u1, ty0), ty1);
            float ddx = u0 - cxp, ddy = u1 - cyp;
            ov = (ddx*ddx + ddy*ddy) <= cu.z;
            if (ov) { a4 = gA[g]; b4 = gB[g]; }
        }
        unsigned long long m = __ballot(ov);
        if (lane == 0) sMask[wave] = m;
        __syncthreads();
        int cnt = 0, off = 0;
        #pragma unroll
        for (int w2 = 0; w2 < 4; ++w2) {
            int pc = __popcll(sMask[w2]);
            if (w2 < wave) off += pc;
            cnt += pc;
        }
        if (ov) {
            int pos = off + __popcll(m & ((1ull << lane) - 1ull));
            sG0[pos] = make_float4(u0, u1, a4.x, a4.y);
            sG1[pos] = make_float4(a4.z, a4.w, b4.x, b4.y);
            sB2[pos] = b4.z;
        }
        __syncthreads();

        for (int e = 0; e < cnt; ++e) {
            float4 e0 = sG0[e];
            float4 e1 = sG1[e];
            float  gb = sB2[e];
            float ddx = pxf - e0.x, ddy = pyf - e0.y;
            float power = -0.5f*(e0.z*ddx*ddx + e1.x*ddy*ddy) - e0.w*ddx*ddy;
            float alp = fminf(0.99f, e1.y * __expf(power));
            alp = (power <= 0.f && alp >= (1.0f/255.0f)) ? alp : 0.f;
            float w = (T > 0.0001f) ? alp * T : 0.f;
            aR = fmaf(w, e1.z, aR);
            aG = fmaf(w, e1.w, aG);
            aB = fmaf(w, gb, aB);
            T = T - T * alp;
        }
        int done = (T <= 0.0001f) ? 1 : 0;
        if (__syncthreads_and(done)) break;
    }

    if (inb) {
        int HW = W * H;
        int pix = iy * W + ix;
        out[pix]        = aR;
        out[HW + pix]   = aG;
        out[2*HW + pix] = aB;
    }
}

// ---------------------------------------------------------------------------
extern "C" void kernel_launch(void* const* d_in, const int* in_sizes, int n_in,
                              void* d_out, int out_size, void* d_ws, size_t ws_size,
                              hipStream_t stream) {
    const float* pws        = (const float*)d_in[0];
    const float* shs        = (const float*)d_in[1];
    const float* alphas_raw = (const float*)d_in[2];
    const float* scales_raw = (const float*)d_in[3];
    const float* rots_raw   = (const float*)d_in[4];
    // d_in[5] = us (forward value cancels: u + us - us)
    const float* Rcw        = (const float*)d_in[6];
    const float* tcw        = (const float*)d_in[7];
    const float* intr       = (const float*)d_in[8];

    const int N  = in_sizes[0] / 3;
    const int HW = (out_size - 2 * N) / 3;
    int W = 1; while ((long long)W * W < (long long)HW) ++W;  // square image
    const int H = HW / W;

    float* out   = (float*)d_out;
    float* areas = out + 3 * HW;

    // workspace carve-up (16B-aligned pieces)
    char* ws = (char*)d_ws;
    size_t off = 0;
    unsigned long long* keys = (unsigned long long*)(ws + off); off += (size_t)N * 8;
    unsigned* rank = (unsigned*)(ws + off);                     off += (size_t)N * 4;
    off = (off + 15) & ~(size_t)15;
    float* Pun = (float*)(ws + off);                            off += (size_t)10 * N * 4;
    off = (off + 15) & ~(size_t)15;
    float4* cullv = (float4*)(ws + off);                        off += (size_t)N * 16;
    float4* gA = (float4*)(ws + off);                           off += (size_t)N * 16;
    float4* gB = (float4*)(ws + off);                           off += (size_t)N * 16;

    int gsN = (N + 255) / 256;
    k_pre<<<gsN, 256, 0, stream>>>(pws, shs, alphas_raw, scales_raw, rots_raw,
                                   Rcw, tcw, intr, N, W, H, areas, keys, rank, Pun);
    dim3 rgrid((N + 511) / 512, (N + JC - 1) / JC);
    k_rank_scatter<<<rgrid, 256, 0, stream>>>(keys, N, rank, Pun, gA, gB, cullv);
    int tilesX = (W + 15) / 16, tilesY = (H + 15) / 16;
    int nTiles = tilesX * tilesY;
    k_render<<<nTiles, 256, 0, stream>>>(gA, gB, cullv, N, W, H, out);
}

// Round 3
// 128.262 us; speedup vs baseline: 1.0078x; 1.0078x over previous
//
#include <hip/hip_runtime.h>

// ---------------------------------------------------------------------------
// Kernel 1: per-Gaussian preprocessing. Writes areas, unsorted param SoA,
// depth sort keys, zero-inits rank (rank doubles as arrival-packed slot acc).
// ---------------------------------------------------------------------------
__global__ __launch_bounds__(256) void k_pre(
    const float* __restrict__ pws, const float* __restrict__ shs,
    const float* __restrict__ alphas_raw, const float* __restrict__ scales_raw,
    const float* __restrict__ rots_raw, const float* __restrict__ Rcw,
    const float* __restrict__ tcw, const float* __restrict__ intr,
    int N, int W, int H, float* __restrict__ areas,
    unsigned long long* __restrict__ keys, unsigned* __restrict__ rank,
    float* __restrict__ P)
{
    int i = blockIdx.x * 256 + threadIdx.x;
    if (i >= N) return;
    rank[i] = 0u;

    float R00=Rcw[0],R01=Rcw[1],R02=Rcw[2];
    float R10=Rcw[3],R11=Rcw[4],R12=Rcw[5];
    float R20=Rcw[6],R21=Rcw[7],R22=Rcw[8];
    float t0=tcw[0],t1=tcw[1],t2=tcw[2];
    float fx=intr[0],fy=intr[1],cx=intr[2],cy=intr[3];

    float pwx=pws[i*3+0], pwy=pws[i*3+1], pwz=pws[i*3+2];
    float pcx = R00*pwx + R01*pwy + R02*pwz + t0;
    float pcy = R10*pwx + R11*pwy + R12*pwz + t1;
    float pcz = R20*pwx + R21*pwy + R22*pwz + t2;
    float depth = pcz;
    float zs = (depth > 0.2f) ? depth : 1.0f;
    float u0 = fx * pcx / zs + cx;
    float u1 = fy * pcy / zs + cy;

    float qw=rots_raw[i*4+0], qx=rots_raw[i*4+1], qy=rots_raw[i*4+2], qz=rots_raw[i*4+3];
    float qn = sqrtf(qw*qw + qx*qx + qy*qy + qz*qz);
    qw/=qn; qx/=qn; qy/=qn; qz/=qn;
    float s0 = expf(scales_raw[i*3+0]);
    float s1 = expf(scales_raw[i*3+1]);
    float s2 = expf(scales_raw[i*3+2]);

    float xx=qx*qx, yy=qy*qy, zq=qz*qz;
    float xy=qx*qy, xz=qx*qz, yz=qy*qz;
    float wx=qw*qx, wy=qw*qy, wz=qw*qz;
    float r00=1.f-2.f*(yy+zq), r01=2.f*(xy-wz),     r02=2.f*(xz+wy);
    float r10=2.f*(xy+wz),     r11=1.f-2.f*(xx+zq), r12=2.f*(yz-wx);
    float r20=2.f*(xz-wy),     r21=2.f*(yz+wx),     r22=1.f-2.f*(xx+yy);

    float m00=r00*s0, m01=r01*s1, m02=r02*s2;
    float m10=r10*s0, m11=r11*s1, m12=r12*s2;
    float m20=r20*s0, m21=r21*s1, m22=r22*s2;
    float V00=m00*m00+m01*m01+m02*m02;
    float V01=m00*m10+m01*m11+m02*m12;
    float V02=m00*m20+m01*m21+m02*m22;
    float V11=m10*m10+m11*m11+m12*m12;
    float V12=m10*m20+m11*m21+m12*m22;
    float V22=m20*m20+m21*m21+m22*m22;

    float tanfx = (float)W / (2.f*fx), tanfy = (float)H / (2.f*fy);
    float limx = 1.3f*tanfx, limy = 1.3f*tanfy;
    float txl = fminf(fmaxf(pcx/zs, -limx), limx) * zs;
    float tyl = fminf(fmaxf(pcy/zs, -limy), limy) * zs;
    float iz = 1.f/zs, iz2 = iz*iz;
    float J00 = fx*iz, J02 = -fx*txl*iz2;
    float J11 = fy*iz, J12 = -fy*tyl*iz2;

    float T00=J00*R00+J02*R20, T01=J00*R01+J02*R21, T02=J00*R02+J02*R22;
    float T10=J11*R10+J12*R20, T11=J11*R11+J12*R21, T12=J11*R12+J12*R22;
    float A0=T00*V00+T01*V01+T02*V02;
    float A1=T00*V01+T01*V11+T02*V12;
    float A2=T00*V02+T01*V12+T02*V22;
    float B0=T10*V00+T11*V01+T12*V02;
    float B1=T10*V01+T11*V11+T12*V12;
    float B2=T10*V02+T11*V12+T12*V22;
    float ca = A0*T00+A1*T01+A2*T02 + 0.3f;
    float cb = A0*T10+A1*T11+A2*T12;
    float cc = B0*T10+B1*T11+B2*T12 + 0.3f;

    float det = ca*cc - cb*cb;
    bool valid = (depth > 0.2f) && (det > 0.f);
    float det_s = valid ? det : 1.f;
    float dinv = 1.f/det_s;
    float ci0 =  cc*dinv, ci1 = -cb*dinv, ci2 = ca*dinv;
    float mid = 0.5f*(ca+cc);
    float lam = mid + sqrtf(fmaxf(mid*mid - det, 0.1f));
    float radius = valid ? ceilf(3.f*sqrtf(lam)) : 0.f;
    areas[2*i+0] = radius;
    areas[2*i+1] = radius;

    float alpha = 1.f/(1.f + expf(-alphas_raw[i]));

    float tw0 = -(R00*t0 + R10*t1 + R20*t2);
    float tw1 = -(R01*t0 + R11*t1 + R21*t2);
    float tw2 = -(R02*t0 + R12*t1 + R22*t2);
    float dx_=pwx-tw0, dy_=pwy-tw1, dz_=pwz-tw2;
    float dn = sqrtf(dx_*dx_+dy_*dy_+dz_*dz_);
    float x=dx_/dn, y=dy_/dn, z=dz_/dn;
    float sxx=x*x, syy=y*y, szz=z*z;
    float sxy=x*y, syz=y*z, sxz=x*z;
    const float* sh = shs + i*48;
    float col[3];
    #pragma unroll
    for (int c = 0; c < 3; ++c) {
        float res = 0.28209479177387814f*sh[0*3+c];
        res += -0.4886025119029199f*y*sh[1*3+c]
             +  0.4886025119029199f*z*sh[2*3+c]
             + -0.4886025119029199f*x*sh[3*3+c];
        res +=  1.0925484305920792f*sxy*sh[4*3+c]
             + -1.0925484305920792f*syz*sh[5*3+c]
             +  0.31539156525252005f*(2.f*szz-sxx-syy)*sh[6*3+c]
             + -1.0925484305920792f*sxz*sh[7*3+c]
             +  0.5462742152960396f*(sxx-syy)*sh[8*3+c];
        res += -0.5900435899266435f*y*(3.f*sxx-syy)*sh[9*3+c]
             +  2.890611442640554f*sxy*z*sh[10*3+c]
             + -0.4570457994644658f*y*(4.f*szz-sxx-syy)*sh[11*3+c]
             +  0.3731763325901154f*z*(2.f*szz-3.f*sxx-3.f*syy)*sh[12*3+c]
             + -0.4570457994644658f*x*(4.f*szz-sxx-syy)*sh[13*3+c]
             +  1.445305721320277f*z*(sxx-syy)*sh[14*3+c]
             + -0.5900435899266435f*x*(sxx-3.f*syy)*sh[15*3+c];
        col[c] = fmaxf(res + 0.5f, 0.f);
    }

    float rc2;
    if (!valid || 255.f*alpha < 0.999f) {
        rc2 = -1.f;
    } else {
        float r2 = 2.f*lam*logf(255.f*alpha);
        float r  = sqrtf(fmaxf(r2, 0.f)) + 1.f;
        rc2 = r*r;
    }

    P[0*N+i]=u0;  P[1*N+i]=u1;  P[2*N+i]=ci0; P[3*N+i]=ci1; P[4*N+i]=ci2;
    P[5*N+i]=alpha; P[6*N+i]=col[0]; P[7*N+i]=col[1]; P[8*N+i]=col[2];
    P[9*N+i]=rc2;

    unsigned ud = __float_as_uint(depth);
    ud = (ud & 0x80000000u) ? ~ud : (ud | 0x80000000u);
    keys[i] = ((unsigned long long)ud << 32) | (unsigned)i;
}

// ---------------------------------------------------------------------------
// Kernel 2: O(N^2) rank sort fused with scatter. rank[i] accumulates
// (count | arrivals<<20) from the nJ j-tile blocks via one atomicAdd each
// (device-scope, G12). The block making the LAST arrival for i knows the
// final rank = (old & 0xFFFFF) + c and scatters i's packed params into
// sorted order inline:
//   cull[s] = (u0,u1,rc2,0); gA[s] = (ci0,ci1,ci2,alpha); gB[s] = (r,g,b,0)
// Fields can't interact: rank <= N-1 = 8191 < 2^20; arrivals <= 16.
// ---------------------------------------------------------------------------
#define JC 512
__global__ __launch_bounds__(256) void k_rank_scatter(
    const unsigned long long* __restrict__ keys, int N,
    unsigned* __restrict__ rank, const float* __restrict__ Pun,
    float4* __restrict__ gA, float4* __restrict__ gB,
    float4* __restrict__ cull)
{
    __shared__ unsigned long long sk[JC];
    const int j0 = blockIdx.y * JC;
    const int nJ = gridDim.y;
    for (int t = threadIdx.x; t < JC; t += 256) {
        int j = j0 + t;
        sk[t] = (j < N) ? keys[j] : ~0ull;
    }
    __syncthreads();

    const int i0 = blockIdx.x * 512 + threadIdx.x;
    const int i1 = i0 + 256;
    unsigned long long my0 = (i0 < N) ? keys[i0] : 0ull;
    unsigned long long my1 = (i1 < N) ? keys[i1] : 0ull;

    int c0 = 0, c1 = 0;
    const ulonglong2* sk2 = (const ulonglong2*)sk;
    #pragma unroll 4
    for (int t = 0; t < JC/2; ++t) {
        ulonglong2 kk = sk2[t];
        c0 += (kk.x < my0) ? 1 : 0;
        c0 += (kk.y < my0) ? 1 : 0;
        c1 += (kk.x < my1) ? 1 : 0;
        c1 += (kk.y < my1) ? 1 : 0;
    }
    if (i0 < N) {
        unsigned old = atomicAdd(&rank[i0], (unsigned)c0 + (1u << 20));
        if ((int)(old >> 20) == nJ - 1) {
            int s = (int)(old & 0xFFFFFu) + c0;
            cull[s] = make_float4(Pun[0*N+i0], Pun[1*N+i0], Pun[9*N+i0], 0.f);
            gA[s]   = make_float4(Pun[2*N+i0], Pun[3*N+i0], Pun[4*N+i0], Pun[5*N+i0]);
            gB[s]   = make_float4(Pun[6*N+i0], Pun[7*N+i0], Pun[8*N+i0], 0.f);
        }
    }
    if (i1 < N) {
        unsigned old = atomicAdd(&rank[i1], (unsigned)c1 + (1u << 20));
        if ((int)(old >> 20) == nJ - 1) {
            int s = (int)(old & 0xFFFFFu) + c1;
            cull[s] = make_float4(Pun[0*N+i1], Pun[1*N+i1], Pun[9*N+i1], 0.f);
            gA[s]   = make_float4(Pun[2*N+i1], Pun[3*N+i1], Pun[4*N+i1], Pun[5*N+i1]);
            gB[s]   = make_float4(Pun[6*N+i1], Pun[7*N+i1], Pun[8*N+i1], 0.f);
        }
    }
}

// ---------------------------------------------------------------------------
// Kernel 3: single-pass tile render, software-pipelined.
// 1 block/CU, 4 waves: no TLP to hide latency, so ALL global loads for
// chunk k+1 (cull AND gA/gB, unconditionally) are issued at the top of
// chunk k's iteration and consumed one iteration later. Per-chunk critical
// path is then ballot + 2 barriers + ~3-entry inner loop (~350 cyc) instead
// of two exposed ~300-900 cyc load chains (43 us -> ~5 us predicted).
// Working set cull+gA+gB = 384 KB -> L2-resident across all 32 chunks.
// ---------------------------------------------------------------------------
__global__ __launch_bounds__(256) void k_render(
    const float4* __restrict__ gA, const float4* __restrict__ gB,
    const float4* __restrict__ cull, int N, int W, int H,
    float* __restrict__ out)
{
    const int tid = threadIdx.x;
    const int tilesX = (W + 15) >> 4;
    const int tile = blockIdx.x;
    const int tX = tile % tilesX, tY = tile / tilesX;
    const int ix = (tX << 4) + (tid & 15);
    const int iy = (tY << 4) + (tid >> 4);
    const bool inb = (ix < W) && (iy < H);
    const float pxf = (float)ix, pyf = (float)iy;
    const float tx0 = (float)(tX << 4), ty0 = (float)(tY << 4);
    int tx1i = (tX << 4) + 15; if (tx1i > W-1) tx1i = W-1;
    int ty1i = (tY << 4) + 15; if (ty1i > H-1) ty1i = H-1;
    const float tx1 = (float)tx1i, ty1 = (float)ty1i;

    float T = inb ? 1.f : 0.f;
    float aR = 0.f, aG = 0.f, aB = 0.f;

    __shared__ float4 sG0[256];   // u0,u1,ci0,ci1
    __shared__ float4 sG1[256];   // ci2,alpha,r,g
    __shared__ float  sB2[256];   // b
    __shared__ unsigned long long sMask[4];

    const int wave = tid >> 6, lane = tid & 63;

    // prologue: chunk 0 into registers (rc2=-1 sentinel never passes cull)
    float4 c_cu = make_float4(0.f, 0.f, -1.f, 0.f);
    float4 c_a  = make_float4(0.f, 0.f, 0.f, 0.f);
    float4 c_b  = make_float4(0.f, 0.f, 0.f, 0.f);
    if (tid < N) { c_cu = cull[tid]; c_a = gA[tid]; c_b = gB[tid]; }

    for (int base = 0; base < N; base += 256) {
        // issue next-chunk prefetch first; consumed after this iteration's
        // barriers, so the ~300cy latency hides under compact + inner loop.
        float4 n_cu = make_float4(0.f, 0.f, -1.f, 0.f);
        float4 n_a  = make_float4(0.f, 0.f, 0.f, 0.f);
        float4 n_b  = make_float4(0.f, 0.f, 0.f, 0.f);
        int gn = base + 256 + tid;
        if (gn < N) { n_cu = cull[gn]; n_a = gA[gn]; n_b = gB[gn]; }

        // cull test on current chunk (all data already in regs)
        float cxp = fminf(fmaxf(c_cu.x, tx0), tx1);
        float cyp = fminf(fmaxf(c_cu.y, ty0), ty1);
        float ddx0 = c_cu.x - cxp, ddy0 = c_cu.y - cyp;
        bool ov = (ddx0*ddx0 + ddy0*ddy0) <= c_cu.z;

        unsigned long long m = __ballot(ov);
        if (lane == 0) sMask[wave] = m;
        __syncthreads();
        int cnt = 0, off = 0;
        #pragma unroll
        for (int w2 = 0; w2 < 4; ++w2) {
            int pc = __popcll(sMask[w2]);
            if (w2 < wave) off += pc;
            cnt += pc;
        }
        if (ov) {
            int pos = off + __popcll(m & ((1ull << lane) - 1ull));
            sG0[pos] = make_float4(c_cu.x, c_cu.y, c_a.x, c_a.y);
            sG1[pos] = make_float4(c_a.z, c_a.w, c_b.x, c_b.y);
            sB2[pos] = c_b.z;
        }
        __syncthreads();

        for (int e = 0; e < cnt; ++e) {
            float4 e0 = sG0[e];
            float4 e1 = sG1[e];
            float  gb = sB2[e];
            float ddx = pxf - e0.x, ddy = pyf - e0.y;
            float power = -0.5f*(e0.z*ddx*ddx + e1.x*ddy*ddy) - e0.w*ddx*ddy;
            float alp = fminf(0.99f, e1.y * __expf(power));
            alp = (power <= 0.f && alp >= (1.0f/255.0f)) ? alp : 0.f;
            float w = (T > 0.0001f) ? alp * T : 0.f;
            aR = fmaf(w, e1.z, aR);
            aG = fmaf(w, e1.w, aG);
            aB = fmaf(w, gb, aB);
            T = T - T * alp;
        }
        // doubles as the barrier protecting LDS reuse next iteration
        int done = (T <= 0.0001f) ? 1 : 0;
        if (__syncthreads_and(done)) break;

        c_cu = n_cu; c_a = n_a; c_b = n_b;
    }

    if (inb) {
        int HW = W * H;
        int pix = iy * W + ix;
        out[pix]        = aR;
        out[HW + pix]   = aG;
        out[2*HW + pix] = aB;
    }
}

// ---------------------------------------------------------------------------
extern "C" void kernel_launch(void* const* d_in, const int* in_sizes, int n_in,
                              void* d_out, int out_size, void* d_ws, size_t ws_size,
                              hipStream_t stream) {
    const float* pws        = (const float*)d_in[0];
    const float* shs        = (const float*)d_in[1];
    const float* alphas_raw = (const float*)d_in[2];
    const float* scales_raw = (const float*)d_in[3];
    const float* rots_raw   = (const float*)d_in[4];
    // d_in[5] = us (forward value cancels: u + us - us)
    const float* Rcw        = (const float*)d_in[6];
    const float* tcw        = (const float*)d_in[7];
    const float* intr       = (const float*)d_in[8];

    const int N  = in_sizes[0] / 3;
    const int HW = (out_size - 2 * N) / 3;
    int W = 1; while ((long long)W * W < (long long)HW) ++W;  // square image
    const int H = HW / W;

    float* out   = (float*)d_out;
    float* areas = out + 3 * HW;

    // workspace carve-up (16B-aligned pieces)
    char* ws = (char*)d_ws;
    size_t off = 0;
    unsigned long long* keys = (unsigned long long*)(ws + off); off += (size_t)N * 8;
    unsigned* rank = (unsigned*)(ws + off);                     off += (size_t)N * 4;
    off = (off + 15) & ~(size_t)15;
    float* Pun = (float*)(ws + off);                            off += (size_t)10 * N * 4;
    off = (off + 15) & ~(size_t)15;
    float4* cullv = (float4*)(ws + off);                        off += (size_t)N * 16;
    float4* gA = (float4*)(ws + off);                           off += (size_t)N * 16;
    float4* gB = (float4*)(ws + off);                           off += (size_t)N * 16;

    int gsN = (N + 255) / 256;
    k_pre<<<gsN, 256, 0, stream>>>(pws, shs, alphas_raw, scales_raw, rots_raw,
                                   Rcw, tcw, intr, N, W, H, areas, keys, rank, Pun);
    dim3 rgrid((N + 511) / 512, (N + JC - 1) / JC);
    k_rank_scatter<<<rgrid, 256, 0, stream>>>(keys, N, rank, Pun, gA, gB, cullv);
    int tilesX = (W + 15) / 16, tilesY = (H + 15) / 16;
    int nTiles = tilesX * tilesY;
    k_render<<<nTiles, 256, 0, stream>>>(gA, gB, cullv, N, W, H, out);
}

// Round 4
// 110.252 us; speedup vs baseline: 1.1725x; 1.1634x over previous
//
#include <hip/hip_runtime.h>

// ---------------------------------------------------------------------------
// Kernel 1: per-Gaussian preprocessing. Writes areas, unsorted param SoA,
// depth sort keys, zero-inits rank (rank doubles as arrival-packed slot acc).
// ---------------------------------------------------------------------------
__global__ __launch_bounds__(256) void k_pre(
    const float* __restrict__ pws, const float* __restrict__ shs,
    const float* __restrict__ alphas_raw, const float* __restrict__ scales_raw,
    const float* __restrict__ rots_raw, const float* __restrict__ Rcw,
    const float* __restrict__ tcw, const float* __restrict__ intr,
    int N, int W, int H, float* __restrict__ areas,
    unsigned long long* __restrict__ keys, unsigned* __restrict__ rank,
    float* __restrict__ P)
{
    int i = blockIdx.x * 256 + threadIdx.x;
    if (i >= N) return;
    rank[i] = 0u;

    float R00=Rcw[0],R01=Rcw[1],R02=Rcw[2];
    float R10=Rcw[3],R11=Rcw[4],R12=Rcw[5];
    float R20=Rcw[6],R21=Rcw[7],R22=Rcw[8];
    float t0=tcw[0],t1=tcw[1],t2=tcw[2];
    float fx=intr[0],fy=intr[1],cx=intr[2],cy=intr[3];

    float pwx=pws[i*3+0], pwy=pws[i*3+1], pwz=pws[i*3+2];
    float pcx = R00*pwx + R01*pwy + R02*pwz + t0;
    float pcy = R10*pwx + R11*pwy + R12*pwz + t1;
    float pcz = R20*pwx + R21*pwy + R22*pwz + t2;
    float depth = pcz;
    float zs = (depth > 0.2f) ? depth : 1.0f;
    float u0 = fx * pcx / zs + cx;
    float u1 = fy * pcy / zs + cy;

    float qw=rots_raw[i*4+0], qx=rots_raw[i*4+1], qy=rots_raw[i*4+2], qz=rots_raw[i*4+3];
    float qn = sqrtf(qw*qw + qx*qx + qy*qy + qz*qz);
    qw/=qn; qx/=qn; qy/=qn; qz/=qn;
    float s0 = expf(scales_raw[i*3+0]);
    float s1 = expf(scales_raw[i*3+1]);
    float s2 = expf(scales_raw[i*3+2]);

    float xx=qx*qx, yy=qy*qy, zq=qz*qz;
    float xy=qx*qy, xz=qx*qz, yz=qy*qz;
    float wx=qw*qx, wy=qw*qy, wz=qw*qz;
    float r00=1.f-2.f*(yy+zq), r01=2.f*(xy-wz),     r02=2.f*(xz+wy);
    float r10=2.f*(xy+wz),     r11=1.f-2.f*(xx+zq), r12=2.f*(yz-wx);
    float r20=2.f*(xz-wy),     r21=2.f*(yz+wx),     r22=1.f-2.f*(xx+yy);

    float m00=r00*s0, m01=r01*s1, m02=r02*s2;
    float m10=r10*s0, m11=r11*s1, m12=r12*s2;
    float m20=r20*s0, m21=r21*s1, m22=r22*s2;
    float V00=m00*m00+m01*m01+m02*m02;
    float V01=m00*m10+m01*m11+m02*m12;
    float V02=m00*m20+m01*m21+m02*m22;
    float V11=m10*m10+m11*m11+m12*m12;
    float V12=m10*m20+m11*m21+m12*m22;
    float V22=m20*m20+m21*m21+m22*m22;

    float tanfx = (float)W / (2.f*fx), tanfy = (float)H / (2.f*fy);
    float limx = 1.3f*tanfx, limy = 1.3f*tanfy;
    float txl = fminf(fmaxf(pcx/zs, -limx), limx) * zs;
    float tyl = fminf(fmaxf(pcy/zs, -limy), limy) * zs;
    float iz = 1.f/zs, iz2 = iz*iz;
    float J00 = fx*iz, J02 = -fx*txl*iz2;
    float J11 = fy*iz, J12 = -fy*tyl*iz2;

    float T00=J00*R00+J02*R20, T01=J00*R01+J02*R21, T02=J00*R02+J02*R22;
    float T10=J11*R10+J12*R20, T11=J11*R11+J12*R21, T12=J11*R12+J12*R22;
    float A0=T00*V00+T01*V01+T02*V02;
    float A1=T00*V01+T01*V11+T02*V12;
    float A2=T00*V02+T01*V12+T02*V22;
    float B0=T10*V00+T11*V01+T12*V02;
    float B1=T10*V01+T11*V11+T12*V12;
    float B2=T10*V02+T11*V12+T12*V22;
    float ca = A0*T00+A1*T01+A2*T02 + 0.3f;
    float cb = A0*T10+A1*T11+A2*T12;
    float cc = B0*T10+B1*T11+B2*T12 + 0.3f;

    float det = ca*cc - cb*cb;
    bool valid = (depth > 0.2f) && (det > 0.f);
    float det_s = valid ? det : 1.f;
    float dinv = 1.f/det_s;
    float ci0 =  cc*dinv, ci1 = -cb*dinv, ci2 = ca*dinv;
    float mid = 0.5f*(ca+cc);
    float lam = mid + sqrtf(fmaxf(mid*mid - det, 0.1f));
    float radius = valid ? ceilf(3.f*sqrtf(lam)) : 0.f;
    areas[2*i+0] = radius;
    areas[2*i+1] = radius;

    float alpha = 1.f/(1.f + expf(-alphas_raw[i]));

    float tw0 = -(R00*t0 + R10*t1 + R20*t2);
    float tw1 = -(R01*t0 + R11*t1 + R21*t2);
    float tw2 = -(R02*t0 + R12*t1 + R22*t2);
    float dx_=pwx-tw0, dy_=pwy-tw1, dz_=pwz-tw2;
    float dn = sqrtf(dx_*dx_+dy_*dy_+dz_*dz_);
    float x=dx_/dn, y=dy_/dn, z=dz_/dn;
    float sxx=x*x, syy=y*y, szz=z*z;
    float sxy=x*y, syz=y*z, sxz=x*z;
    const float* sh = shs + i*48;
    float col[3];
    #pragma unroll
    for (int c = 0; c < 3; ++c) {
        float res = 0.28209479177387814f*sh[0*3+c];
        res += -0.4886025119029199f*y*sh[1*3+c]
             +  0.4886025119029199f*z*sh[2*3+c]
             + -0.4886025119029199f*x*sh[3*3+c];
        res +=  1.0925484305920792f*sxy*sh[4*3+c]
             + -1.0925484305920792f*syz*sh[5*3+c]
             +  0.31539156525252005f*(2.f*szz-sxx-syy)*sh[6*3+c]
             + -1.0925484305920792f*sxz*sh[7*3+c]
             +  0.5462742152960396f*(sxx-syy)*sh[8*3+c];
        res += -0.5900435899266435f*y*(3.f*sxx-syy)*sh[9*3+c]
             +  2.890611442640554f*sxy*z*sh[10*3+c]
             + -0.4570457994644658f*y*(4.f*szz-sxx-syy)*sh[11*3+c]
             +  0.3731763325901154f*z*(2.f*szz-3.f*sxx-3.f*syy)*sh[12*3+c]
             + -0.4570457994644658f*x*(4.f*szz-sxx-syy)*sh[13*3+c]
             +  1.445305721320277f*z*(sxx-syy)*sh[14*3+c]
             + -0.5900435899266435f*x*(sxx-3.f*syy)*sh[15*3+c];
        col[c] = fmaxf(res + 0.5f, 0.f);
    }

    float rc2;
    if (!valid || 255.f*alpha < 0.999f) {
        rc2 = -1.f;
    } else {
        float r2 = 2.f*lam*logf(255.f*alpha);
        float r  = sqrtf(fmaxf(r2, 0.f)) + 1.f;
        rc2 = r*r;
    }

    P[0*N+i]=u0;  P[1*N+i]=u1;  P[2*N+i]=ci0; P[3*N+i]=ci1; P[4*N+i]=ci2;
    P[5*N+i]=alpha; P[6*N+i]=col[0]; P[7*N+i]=col[1]; P[8*N+i]=col[2];
    P[9*N+i]=rc2;

    unsigned ud = __float_as_uint(depth);
    ud = (ud & 0x80000000u) ? ~ud : (ud | 0x80000000u);
    keys[i] = ((unsigned long long)ud << 32) | (unsigned)i;
}

// ---------------------------------------------------------------------------
// Kernel 2: O(N^2) rank sort fused with scatter. rank[i] accumulates
// (count | arrivals<<20) from the nJ j-tile blocks via one atomicAdd each
// (device-scope, G12). The block making the LAST arrival for i knows the
// final rank = (old & 0xFFFFF) + c and scatters i's packed params into
// sorted order inline:
//   cull[s] = (u0,u1,rc2,0); gA[s] = (ci0,ci1,ci2,alpha); gB[s] = (r,g,b,0)
// Fields can't interact: rank <= N-1 = 8191 < 2^20; arrivals <= 16.
// ---------------------------------------------------------------------------
#define JC 512
__global__ __launch_bounds__(256) void k_rank_scatter(
    const unsigned long long* __restrict__ keys, int N,
    unsigned* __restrict__ rank, const float* __restrict__ Pun,
    float4* __restrict__ gA, float4* __restrict__ gB,
    float4* __restrict__ cull)
{
    __shared__ unsigned long long sk[JC];
    const int j0 = blockIdx.y * JC;
    const int nJ = gridDim.y;
    for (int t = threadIdx.x; t < JC; t += 256) {
        int j = j0 + t;
        sk[t] = (j < N) ? keys[j] : ~0ull;
    }
    __syncthreads();

    const int i0 = blockIdx.x * 512 + threadIdx.x;
    const int i1 = i0 + 256;
    unsigned long long my0 = (i0 < N) ? keys[i0] : 0ull;
    unsigned long long my1 = (i1 < N) ? keys[i1] : 0ull;

    int c0 = 0, c1 = 0;
    const ulonglong2* sk2 = (const ulonglong2*)sk;
    #pragma unroll 4
    for (int t = 0; t < JC/2; ++t) {
        ulonglong2 kk = sk2[t];
        c0 += (kk.x < my0) ? 1 : 0;
        c0 += (kk.y < my0) ? 1 : 0;
        c1 += (kk.x < my1) ? 1 : 0;
        c1 += (kk.y < my1) ? 1 : 0;
    }
    if (i0 < N) {
        unsigned old = atomicAdd(&rank[i0], (unsigned)c0 + (1u << 20));
        if ((int)(old >> 20) == nJ - 1) {
            int s = (int)(old & 0xFFFFFu) + c0;
            cull[s] = make_float4(Pun[0*N+i0], Pun[1*N+i0], Pun[9*N+i0], 0.f);
            gA[s]   = make_float4(Pun[2*N+i0], Pun[3*N+i0], Pun[4*N+i0], Pun[5*N+i0]);
            gB[s]   = make_float4(Pun[6*N+i0], Pun[7*N+i0], Pun[8*N+i0], 0.f);
        }
    }
    if (i1 < N) {
        unsigned old = atomicAdd(&rank[i1], (unsigned)c1 + (1u << 20));
        if ((int)(old >> 20) == nJ - 1) {
            int s = (int)(old & 0xFFFFFu) + c1;
            cull[s] = make_float4(Pun[0*N+i1], Pun[1*N+i1], Pun[9*N+i1], 0.f);
            gA[s]   = make_float4(Pun[2*N+i1], Pun[3*N+i1], Pun[4*N+i1], Pun[5*N+i1]);
            gB[s]   = make_float4(Pun[6*N+i1], Pun[7*N+i1], Pun[8*N+i1], 0.f);
        }
    }
}

// ---------------------------------------------------------------------------
// Kernel 3: render, ONE WAVE (64 threads) per block on an 8x8 pixel tile.
// Grid = nTiles8 * nseg blocks = 1024 * 8 = 8192 = 32 waves/CU (HW cap),
// vs 1 wave/SIMD in the 256-thread/16x16 variant. Round-3 lesson: the
// ~2500 cyc/chunk of distributed stalls (LDS latency, compaction chains)
// is hidden by TLP, not by in-block prefetch. Single-wave blocks need NO
// __syncthreads at all: ballot/compaction is wave-synchronous and LDS is
// program-ordered within the wave. Local-T segmentation as in rounds 0/1
// (passed): C = C0 + T0*C1 associativity, combine kernel folds segments.
// ---------------------------------------------------------------------------
__global__ __launch_bounds__(64) void k_render(
    const float4* __restrict__ gA, const float4* __restrict__ gB,
    const float4* __restrict__ cull, int N, int W, int H,
    int nTiles, int nseg, float4* __restrict__ segbuf)
{
    const int lane = threadIdx.x;
    const int tilesX = (W + 7) >> 3;
    const int tile = blockIdx.x % nTiles, seg = blockIdx.x / nTiles;
    const int tX = tile % tilesX, tY = tile / tilesX;
    const int ix = (tX << 3) + (lane & 7);
    const int iy = (tY << 3) + (lane >> 3);
    const bool inb = (ix < W) && (iy < H);
    const float pxf = (float)ix, pyf = (float)iy;
    const float tx0 = (float)(tX << 3), ty0 = (float)(tY << 3);
    int tx1i = (tX << 3) + 7; if (tx1i > W-1) tx1i = W-1;
    int ty1i = (tY << 3) + 7; if (ty1i > H-1) ty1i = H-1;
    const float tx1 = (float)tx1i, ty1 = (float)ty1i;

    const int per = (N + nseg - 1) / nseg;
    const int g0 = seg * per;
    const int g1 = min(N, g0 + per);

    float T = inb ? 1.f : 0.f;
    float aR = 0.f, aG = 0.f, aB = 0.f;

    __shared__ float4 sG0[64];   // u0,u1,ci0,ci1
    __shared__ float4 sG1[64];   // ci2,alpha,r,g
    __shared__ float  sB2[64];   // b

    for (int base = g0; base < g1; base += 64) {
        int g = base + lane;
        bool ov = false;
        float u0 = 0.f, u1 = 0.f;
        if (g < g1) {
            float4 cu = cull[g];
            u0 = cu.x; u1 = cu.y;
            float cxp = fminf(fmaxf(u0, tx0), tx1);
            float cyp = fminf(fmaxf(u1, ty0), ty1);
            float ddx = u0 - cxp, ddy = u1 - cyp;
            ov = (ddx*ddx + ddy*ddy) <= cu.z;
        }
        unsigned long long m = __ballot(ov);
        int cnt = __popcll(m);
        if (ov) {
            int pos = __popcll(m & ((1ull << lane) - 1ull));
            float4 a4 = gA[g];
            float4 b4 = gB[g];
            sG0[pos] = make_float4(u0, u1, a4.x, a4.y);
            sG1[pos] = make_float4(a4.z, a4.w, b4.x, b4.y);
            sB2[pos] = b4.z;
        }
        // wave-synchronous: LDS writes above are program-ordered before reads
        for (int e = 0; e < cnt; ++e) {
            float4 e0 = sG0[e];
            float4 e1 = sG1[e];
            float  gb = sB2[e];
            float ddx = pxf - e0.x, ddy = pyf - e0.y;
            float power = -0.5f*(e0.z*ddx*ddx + e1.x*ddy*ddy) - e0.w*ddx*ddy;
            float alp = fminf(0.99f, e1.y * __expf(power));
            alp = (power <= 0.f && alp >= (1.0f/255.0f)) ? alp : 0.f;
            float w = (T > 0.0001f) ? alp * T : 0.f;
            aR = fmaf(w, e1.z, aR);
            aG = fmaf(w, e1.w, aG);
            aB = fmaf(w, gb, aB);
            T = T - T * alp;
        }
        if (__all(T <= 0.0001f)) break;
    }

    if (inb) {
        int pix = iy * W + ix;
        segbuf[(size_t)seg * (size_t)(W*H) + pix] = make_float4(T, aR, aG, aB);
    }
}

// ---------------------------------------------------------------------------
// Kernel 4: combine depth segments front-to-back.
// ---------------------------------------------------------------------------
__global__ __launch_bounds__(256) void k_combine(
    const float4* __restrict__ segbuf, int HW, int nseg,
    float* __restrict__ out)
{
    int p = blockIdx.x * 256 + threadIdx.x;
    if (p >= HW) return;
    float T = 1.f, r = 0.f, g = 0.f, b = 0.f;
    for (int s = 0; s < nseg; ++s) {
        float4 v = segbuf[(size_t)s * HW + p];
        r = fmaf(T, v.y, r);
        g = fmaf(T, v.z, g);
        b = fmaf(T, v.w, b);
        T *= v.x;
    }
    out[p] = r; out[HW + p] = g; out[2*HW + p] = b;
}

// ---------------------------------------------------------------------------
extern "C" void kernel_launch(void* const* d_in, const int* in_sizes, int n_in,
                              void* d_out, int out_size, void* d_ws, size_t ws_size,
                              hipStream_t stream) {
    const float* pws        = (const float*)d_in[0];
    const float* shs        = (const float*)d_in[1];
    const float* alphas_raw = (const float*)d_in[2];
    const float* scales_raw = (const float*)d_in[3];
    const float* rots_raw   = (const float*)d_in[4];
    // d_in[5] = us (forward value cancels: u + us - us)
    const float* Rcw        = (const float*)d_in[6];
    const float* tcw        = (const float*)d_in[7];
    const float* intr       = (const float*)d_in[8];

    const int N  = in_sizes[0] / 3;
    const int HW = (out_size - 2 * N) / 3;
    int W = 1; while ((long long)W * W < (long long)HW) ++W;  // square image
    const int H = HW / W;

    float* out   = (float*)d_out;
    float* areas = out + 3 * HW;

    // workspace carve-up (16B-aligned pieces)
    char* ws = (char*)d_ws;
    size_t off = 0;
    unsigned long long* keys = (unsigned long long*)(ws + off); off += (size_t)N * 8;
    unsigned* rank = (unsigned*)(ws + off);                     off += (size_t)N * 4;
    off = (off + 15) & ~(size_t)15;
    float* Pun = (float*)(ws + off);                            off += (size_t)10 * N * 4;
    off = (off + 15) & ~(size_t)15;
    float4* cullv = (float4*)(ws + off);                        off += (size_t)N * 16;
    float4* gA = (float4*)(ws + off);                           off += (size_t)N * 16;
    float4* gB = (float4*)(ws + off);                           off += (size_t)N * 16;
    float4* segbuf = (float4*)(ws + off);
    size_t remain = (ws_size > off) ? (ws_size - off) : 0;
    int nseg = 8;
    while (nseg > 1 && (size_t)nseg * (size_t)HW * 16 > remain) nseg >>= 1;

    int gsN = (N + 255) / 256;
    k_pre<<<gsN, 256, 0, stream>>>(pws, shs, alphas_raw, scales_raw, rots_raw,
                                   Rcw, tcw, intr, N, W, H, areas, keys, rank, Pun);
    dim3 rgrid((N + 511) / 512, (N + JC - 1) / JC);
    k_rank_scatter<<<rgrid, 256, 0, stream>>>(keys, N, rank, Pun, gA, gB, cullv);
    int tilesX = (W + 7) / 8, tilesY = (H + 7) / 8;
    int nTiles = tilesX * tilesY;
    k_render<<<nTiles * nseg, 64, 0, stream>>>(gA, gB, cullv, N, W, H,
                                               nTiles, nseg, segbuf);
    k_combine<<<(HW + 255) / 256, 256, 0, stream>>>(segbuf, HW, nseg, out);
}

// Round 5
// 108.422 us; speedup vs baseline: 1.1922x; 1.0169x over previous
//
#include <hip/hip_runtime.h>

// ---------------------------------------------------------------------------
// Kernel 1: per-Gaussian preprocessing. 64-thread blocks (128 blocks) so the
// latency-bound transcendental+load chain spreads over 128 CUs instead of 32.
// Writes areas, unsorted param SoA, depth sort keys, zero-inits rank.
// ---------------------------------------------------------------------------
__global__ __launch_bounds__(64) void k_pre(
    const float* __restrict__ pws, const float* __restrict__ shs,
    const float* __restrict__ alphas_raw, const float* __restrict__ scales_raw,
    const float* __restrict__ rots_raw, const float* __restrict__ Rcw,
    const float* __restrict__ tcw, const float* __restrict__ intr,
    int N, int W, int H, float* __restrict__ areas,
    unsigned long long* __restrict__ keys, unsigned* __restrict__ rank,
    float* __restrict__ P)
{
    int i = blockIdx.x * 64 + threadIdx.x;
    if (i >= N) return;
    rank[i] = 0u;

    float R00=Rcw[0],R01=Rcw[1],R02=Rcw[2];
    float R10=Rcw[3],R11=Rcw[4],R12=Rcw[5];
    float R20=Rcw[6],R21=Rcw[7],R22=Rcw[8];
    float t0=tcw[0],t1=tcw[1],t2=tcw[2];
    float fx=intr[0],fy=intr[1],cx=intr[2],cy=intr[3];

    float pwx=pws[i*3+0], pwy=pws[i*3+1], pwz=pws[i*3+2];
    float pcx = R00*pwx + R01*pwy + R02*pwz + t0;
    float pcy = R10*pwx + R11*pwy + R12*pwz + t1;
    float pcz = R20*pwx + R21*pwy + R22*pwz + t2;
    float depth = pcz;
    float zs = (depth > 0.2f) ? depth : 1.0f;
    float u0 = fx * pcx / zs + cx;
    float u1 = fy * pcy / zs + cy;

    float4 q4 = *reinterpret_cast<const float4*>(rots_raw + i*4);
    float qw=q4.x, qx=q4.y, qy=q4.z, qz=q4.w;
    float qn = sqrtf(qw*qw + qx*qx + qy*qy + qz*qz);
    qw/=qn; qx/=qn; qy/=qn; qz/=qn;
    float s0 = expf(scales_raw[i*3+0]);
    float s1 = expf(scales_raw[i*3+1]);
    float s2 = expf(scales_raw[i*3+2]);

    float xx=qx*qx, yy=qy*qy, zq=qz*qz;
    float xy=qx*qy, xz=qx*qz, yz=qy*qz;
    float wx=qw*qx, wy=qw*qy, wz=qw*qz;
    float r00=1.f-2.f*(yy+zq), r01=2.f*(xy-wz),     r02=2.f*(xz+wy);
    float r10=2.f*(xy+wz),     r11=1.f-2.f*(xx+zq), r12=2.f*(yz-wx);
    float r20=2.f*(xz-wy),     r21=2.f*(yz+wx),     r22=1.f-2.f*(xx+yy);

    float m00=r00*s0, m01=r01*s1, m02=r02*s2;
    float m10=r10*s0, m11=r11*s1, m12=r12*s2;
    float m20=r20*s0, m21=r21*s1, m22=r22*s2;
    float V00=m00*m00+m01*m01+m02*m02;
    float V01=m00*m10+m01*m11+m02*m12;
    float V02=m00*m20+m01*m21+m02*m22;
    float V11=m10*m10+m11*m11+m12*m12;
    float V12=m10*m20+m11*m21+m12*m22;
    float V22=m20*m20+m21*m21+m22*m22;

    float tanfx = (float)W / (2.f*fx), tanfy = (float)H / (2.f*fy);
    float limx = 1.3f*tanfx, limy = 1.3f*tanfy;
    float txl = fminf(fmaxf(pcx/zs, -limx), limx) * zs;
    float tyl = fminf(fmaxf(pcy/zs, -limy), limy) * zs;
    float iz = 1.f/zs, iz2 = iz*iz;
    float J00 = fx*iz, J02 = -fx*txl*iz2;
    float J11 = fy*iz, J12 = -fy*tyl*iz2;

    float T00=J00*R00+J02*R20, T01=J00*R01+J02*R21, T02=J00*R02+J02*R22;
    float T10=J11*R10+J12*R20, T11=J11*R11+J12*R21, T12=J11*R12+J12*R22;
    float A0=T00*V00+T01*V01+T02*V02;
    float A1=T00*V01+T01*V11+T02*V12;
    float A2=T00*V02+T01*V12+T02*V22;
    float B0=T10*V00+T11*V01+T12*V02;
    float B1=T10*V01+T11*V11+T12*V12;
    float B2=T10*V02+T11*V12+T12*V22;
    float ca = A0*T00+A1*T01+A2*T02 + 0.3f;
    float cb = A0*T10+A1*T11+A2*T12;
    float cc = B0*T10+B1*T11+B2*T12 + 0.3f;

    float det = ca*cc - cb*cb;
    bool valid = (depth > 0.2f) && (det > 0.f);
    float det_s = valid ? det : 1.f;
    float dinv = 1.f/det_s;
    float ci0 =  cc*dinv, ci1 = -cb*dinv, ci2 = ca*dinv;
    float mid = 0.5f*(ca+cc);
    float lam = mid + sqrtf(fmaxf(mid*mid - det, 0.1f));
    float radius = valid ? ceilf(3.f*sqrtf(lam)) : 0.f;
    areas[2*i+0] = radius;
    areas[2*i+1] = radius;

    float alpha = 1.f/(1.f + expf(-alphas_raw[i]));

    float tw0 = -(R00*t0 + R10*t1 + R20*t2);
    float tw1 = -(R01*t0 + R11*t1 + R21*t2);
    float tw2 = -(R02*t0 + R12*t1 + R22*t2);
    float dx_=pwx-tw0, dy_=pwy-tw1, dz_=pwz-tw2;
    float dn = sqrtf(dx_*dx_+dy_*dy_+dz_*dz_);
    float x=dx_/dn, y=dy_/dn, z=dz_/dn;
    float sxx=x*x, syy=y*y, szz=z*z;
    float sxy=x*y, syz=y*z, sxz=x*z;

    // 48 SH coeffs via 12 explicit float4 loads (base is 192B-aligned)
    float shl[48];
    const float4* sh4 = reinterpret_cast<const float4*>(shs + i*48);
    #pragma unroll
    for (int k = 0; k < 12; ++k) {
        float4 v = sh4[k];
        shl[4*k+0]=v.x; shl[4*k+1]=v.y; shl[4*k+2]=v.z; shl[4*k+3]=v.w;
    }
    float col[3];
    #pragma unroll
    for (int c = 0; c < 3; ++c) {
        float res = 0.28209479177387814f*shl[0*3+c];
        res += -0.4886025119029199f*y*shl[1*3+c]
             +  0.4886025119029199f*z*shl[2*3+c]
             + -0.4886025119029199f*x*shl[3*3+c];
        res +=  1.0925484305920792f*sxy*shl[4*3+c]
             + -1.0925484305920792f*syz*shl[5*3+c]
             +  0.31539156525252005f*(2.f*szz-sxx-syy)*shl[6*3+c]
             + -1.0925484305920792f*sxz*shl[7*3+c]
             +  0.5462742152960396f*(sxx-syy)*shl[8*3+c];
        res += -0.5900435899266435f*y*(3.f*sxx-syy)*shl[9*3+c]
             +  2.890611442640554f*sxy*z*shl[10*3+c]
             + -0.4570457994644658f*y*(4.f*szz-sxx-syy)*shl[11*3+c]
             +  0.3731763325901154f*z*(2.f*szz-3.f*sxx-3.f*syy)*shl[12*3+c]
             + -0.4570457994644658f*x*(4.f*szz-sxx-syy)*shl[13*3+c]
             +  1.445305721320277f*z*(sxx-syy)*shl[14*3+c]
             + -0.5900435899266435f*x*(sxx-3.f*syy)*shl[15*3+c];
        col[c] = fmaxf(res + 0.5f, 0.f);
    }

    float rc2;
    if (!valid || 255.f*alpha < 0.999f) {
        rc2 = -1.f;
    } else {
        float r2 = 2.f*lam*logf(255.f*alpha);
        float r  = sqrtf(fmaxf(r2, 0.f)) + 1.f;
        rc2 = r*r;
    }

    P[0*N+i]=u0;  P[1*N+i]=u1;  P[2*N+i]=ci0; P[3*N+i]=ci1; P[4*N+i]=ci2;
    P[5*N+i]=alpha; P[6*N+i]=col[0]; P[7*N+i]=col[1]; P[8*N+i]=col[2];
    P[9*N+i]=rc2;

    unsigned ud = __float_as_uint(depth);
    ud = (ud & 0x80000000u) ? ~ud : (ud | 0x80000000u);
    keys[i] = ((unsigned long long)ud << 32) | (unsigned)i;
}

// ---------------------------------------------------------------------------
// Kernel 2: O(N^2) rank sort fused with scatter. One i per thread now
// (512 blocks -> 2 WGs/CU, half the per-thread serial compare chain of the
// 2-i version). rank[i] accumulates (count | arrivals<<20) from the nJ
// j-tile blocks via one atomicAdd each (device-scope, G12). The block making
// the LAST arrival for i knows the final rank and scatters i's packed params:
//   cull[s] = (u0,u1,rc2,0); gA[s] = (ci0,ci1,ci2,alpha); gB[s] = (r,g,b,0)
// Fields can't interact: rank <= N-1 = 8191 < 2^20; arrivals <= 16.
// ---------------------------------------------------------------------------
#define JC 512
__global__ __launch_bounds__(256) void k_rank_scatter(
    const unsigned long long* __restrict__ keys, int N,
    unsigned* __restrict__ rank, const float* __restrict__ Pun,
    float4* __restrict__ gA, float4* __restrict__ gB,
    float4* __restrict__ cull)
{
    __shared__ unsigned long long sk[JC];
    const int j0 = blockIdx.y * JC;
    const int nJ = gridDim.y;
    for (int t = threadIdx.x; t < JC; t += 256) {
        int j = j0 + t;
        sk[t] = (j < N) ? keys[j] : ~0ull;
    }
    __syncthreads();

    const int i = blockIdx.x * 256 + threadIdx.x;
    unsigned long long my = (i < N) ? keys[i] : 0ull;

    int c = 0;
    const ulonglong2* sk2 = (const ulonglong2*)sk;
    #pragma unroll 4
    for (int t = 0; t < JC/2; ++t) {
        ulonglong2 kk = sk2[t];
        c += (kk.x < my) ? 1 : 0;
        c += (kk.y < my) ? 1 : 0;
    }
    if (i < N) {
        unsigned old = atomicAdd(&rank[i], (unsigned)c + (1u << 20));
        if ((int)(old >> 20) == nJ - 1) {
            int s = (int)(old & 0xFFFFFu) + c;
            cull[s] = make_float4(Pun[0*N+i], Pun[1*N+i], Pun[9*N+i], 0.f);
            gA[s]   = make_float4(Pun[2*N+i], Pun[3*N+i], Pun[4*N+i], Pun[5*N+i]);
            gB[s]   = make_float4(Pun[6*N+i], Pun[7*N+i], Pun[8*N+i], 0.f);
        }
    }
}

// ---------------------------------------------------------------------------
// Kernel 3: render. 256-thread blocks = 4 INDEPENDENT waves, each wave owns
// one 8x8 tile of a 2x2 super-tile, all at the same depth segment (so the 4
// waves stream the SAME cull chunks -> L1 hits). Zero __syncthreads: ballot/
// compaction is wave-synchronous, LDS stages are wave-private [4][64].
// 256 super-tiles * 8 segs = 2048 blocks * 4 waves = 32 waves/CU at only
// 8 WGs/CU (r4's 1-wave WGs plausibly hit the ~16 WG/CU slot cap = half
// occupancy; r0/r1's 4-wave WGs burned time in 2 barriers/chunk).
// __launch_bounds__(256,8) pins <=64 VGPR so 8 waves/SIMD is guaranteed.
// Local-T segmentation as rounds 0/1/4 (passed): C = C0 + T0*C1.
// ---------------------------------------------------------------------------
__global__ __launch_bounds__(256, 8) void k_render(
    const float4* __restrict__ gA, const float4* __restrict__ gB,
    const float4* __restrict__ cull, int N, int W, int H,
    int nSuper, int superX, int tilesX, int tilesY, int nseg,
    float4* __restrict__ segbuf)
{
    const int tid  = threadIdx.x;
    const int wv   = tid >> 6, lane = tid & 63;
    const int sup  = blockIdx.x % nSuper, seg = blockIdx.x / nSuper;
    const int sX   = sup % superX, sY = sup / superX;
    const int tX   = (sX << 1) + (wv & 1);
    const int tY   = (sY << 1) + (wv >> 1);
    const bool tOK = (tX < tilesX) && (tY < tilesY);
    const int ix = (tX << 3) + (lane & 7);
    const int iy = (tY << 3) + (lane >> 3);
    const bool inb = tOK && (ix < W) && (iy < H);
    const float pxf = (float)ix, pyf = (float)iy;
    const float tx0 = (float)(tX << 3), ty0 = (float)(tY << 3);
    int tx1i = (tX << 3) + 7; if (tx1i > W-1) tx1i = W-1;
    int ty1i = (tY << 3) + 7; if (ty1i > H-1) ty1i = H-1;
    const float tx1 = (float)tx1i, ty1 = (float)ty1i;

    const int per = (N + nseg - 1) / nseg;
    const int g0 = seg * per;
    const int g1 = min(N, g0 + per);

    float T = inb ? 1.f : 0.f;
    float aR = 0.f, aG = 0.f, aB = 0.f;

    __shared__ float4 sG0[4][64];   // u0,u1,ci0,ci1   (wave-private slice)
    __shared__ float4 sG1[4][64];   // ci2,alpha,r,g
    __shared__ float  sB2[4][64];   // b

    if (tOK) {
        for (int base = g0; base < g1; base += 64) {
            int g = base + lane;
            bool ov = false;
            float u0 = 0.f, u1 = 0.f;
            if (g < g1) {
                float4 cu = cull[g];
                u0 = cu.x; u1 = cu.y;
                float cxp = fminf(fmaxf(u0, tx0), tx1);
                float cyp = fminf(fmaxf(u1, ty0), ty1);
                float ddx = u0 - cxp, ddy = u1 - cyp;
                ov = (ddx*ddx + ddy*ddy) <= cu.z;
            }
            unsigned long long m = __ballot(ov);
            int cnt = __popcll(m);
            if (ov) {
                int pos = __popcll(m & ((1ull << lane) - 1ull));
                float4 a4 = gA[g];
                float4 b4 = gB[g];
                sG0[wv][pos] = make_float4(u0, u1, a4.x, a4.y);
                sG1[wv][pos] = make_float4(a4.z, a4.w, b4.x, b4.y);
                sB2[wv][pos] = b4.z;
            }
            // wave-synchronous: same-wave DS ops are program-ordered
            for (int e = 0; e < cnt; ++e) {
                float4 e0 = sG0[wv][e];
                float4 e1 = sG1[wv][e];
                float  gb = sB2[wv][e];
                float ddx = pxf - e0.x, ddy = pyf - e0.y;
                float power = -0.5f*(e0.z*ddx*ddx + e1.x*ddy*ddy) - e0.w*ddx*ddy;
                float alp = fminf(0.99f, e1.y * __expf(power));
                alp = (power <= 0.f && alp >= (1.0f/255.0f)) ? alp : 0.f;
                float w = (T > 0.0001f) ? alp * T : 0.f;
                aR = fmaf(w, e1.z, aR);
                aG = fmaf(w, e1.w, aG);
                aB = fmaf(w, gb, aB);
                T = T - T * alp;
            }
            if (__all(T <= 0.0001f)) break;
        }
    }

    if (inb) {
        int pix = iy * W + ix;
        segbuf[(size_t)seg * (size_t)(W*H) + pix] = make_float4(T, aR, aG, aB);
    }
}

// ---------------------------------------------------------------------------
// Kernel 4: combine depth segments front-to-back.
// ---------------------------------------------------------------------------
__global__ __launch_bounds__(256) void k_combine(
    const float4* __restrict__ segbuf, int HW, int nseg,
    float* __restrict__ out)
{
    int p = blockIdx.x * 256 + threadIdx.x;
    if (p >= HW) return;
    float T = 1.f, r = 0.f, g = 0.f, b = 0.f;
    for (int s = 0; s < nseg; ++s) {
        float4 v = segbuf[(size_t)s * HW + p];
        r = fmaf(T, v.y, r);
        g = fmaf(T, v.z, g);
        b = fmaf(T, v.w, b);
        T *= v.x;
    }
    out[p] = r; out[HW + p] = g; out[2*HW + p] = b;
}

// ---------------------------------------------------------------------------
extern "C" void kernel_launch(void* const* d_in, const int* in_sizes, int n_in,
                              void* d_out, int out_size, void* d_ws, size_t ws_size,
                              hipStream_t stream) {
    const float* pws        = (const float*)d_in[0];
    const float* shs        = (const float*)d_in[1];
    const float* alphas_raw = (const float*)d_in[2];
    const float* scales_raw = (const float*)d_in[3];
    const float* rots_raw   = (const float*)d_in[4];
    // d_in[5] = us (forward value cancels: u + us - us)
    const float* Rcw        = (const float*)d_in[6];
    const float* tcw        = (const float*)d_in[7];
    const float* intr       = (const float*)d_in[8];

    const int N  = in_sizes[0] / 3;
    const int HW = (out_size - 2 * N) / 3;
    int W = 1; while ((long long)W * W < (long long)HW) ++W;  // square image
    const int H = HW / W;

    float* out   = (float*)d_out;
    float* areas = out + 3 * HW;

    // workspace carve-up (16B-aligned pieces)
    char* ws = (char*)d_ws;
    size_t off = 0;
    unsigned long long* keys = (unsigned long long*)(ws + off); off += (size_t)N * 8;
    unsigned* rank = (unsigned*)(ws + off);                     off += (size_t)N * 4;
    off = (off + 15) & ~(size_t)15;
    float* Pun = (float*)(ws + off);                            off += (size_t)10 * N * 4;
    off = (off + 15) & ~(size_t)15;
    float4* cullv = (float4*)(ws + off);                        off += (size_t)N * 16;
    float4* gA = (float4*)(ws + off);                           off += (size_t)N * 16;
    float4* gB = (float4*)(ws + off);                           off += (size_t)N * 16;
    float4* segbuf = (float4*)(ws + off);
    size_t remain = (ws_size > off) ? (ws_size - off) : 0;
    int nseg = 8;
    while (nseg > 1 && (size_t)nseg * (size_t)HW * 16 > remain) nseg >>= 1;

    k_pre<<<(N + 63) / 64, 64, 0, stream>>>(pws, shs, alphas_raw, scales_raw,
                                            rots_raw, Rcw, tcw, intr, N, W, H,
                                            areas, keys, rank, Pun);
    dim3 rgrid((N + 255) / 256, (N + JC - 1) / JC);
    k_rank_scatter<<<rgrid, 256, 0, stream>>>(keys, N, rank, Pun, gA, gB, cullv);
    int tilesX = (W + 7) / 8, tilesY = (H + 7) / 8;
    int superX = (tilesX + 1) / 2, superY = (tilesY + 1) / 2;
    int nSuper = superX * superY;
    k_render<<<nSuper * nseg, 256, 0, stream>>>(gA, gB, cullv, N, W, H,
                                                nSuper, superX, tilesX, tilesY,
                                                nseg, segbuf);
    k_combine<<<(HW + 255) / 256, 256, 0, stream>>>(segbuf, HW, nseg, out);
}

// Round 6
// 108.144 us; speedup vs baseline: 1.1953x; 1.0026x over previous
//
#include <hip/hip_runtime.h>

// ---------------------------------------------------------------------------
// Kernel 1: per-Gaussian preprocessing. 64-thread blocks (128 blocks) so the
// latency-bound transcendental+load chain spreads over 128 CUs instead of 32.
// Writes areas, unsorted param SoA, depth sort keys, zero-inits rank.
// ---------------------------------------------------------------------------
__global__ __launch_bounds__(64) void k_pre(
    const float* __restrict__ pws, const float* __restrict__ shs,
    const float* __restrict__ alphas_raw, const float* __restrict__ scales_raw,
    const float* __restrict__ rots_raw, const float* __restrict__ Rcw,
    const float* __restrict__ tcw, const float* __restrict__ intr,
    int N, int W, int H, float* __restrict__ areas,
    unsigned long long* __restrict__ keys, unsigned* __restrict__ rank,
    float* __restrict__ P)
{
    int i = blockIdx.x * 64 + threadIdx.x;
    if (i >= N) return;
    rank[i] = 0u;

    float R00=Rcw[0],R01=Rcw[1],R02=Rcw[2];
    float R10=Rcw[3],R11=Rcw[4],R12=Rcw[5];
    float R20=Rcw[6],R21=Rcw[7],R22=Rcw[8];
    float t0=tcw[0],t1=tcw[1],t2=tcw[2];
    float fx=intr[0],fy=intr[1],cx=intr[2],cy=intr[3];

    float pwx=pws[i*3+0], pwy=pws[i*3+1], pwz=pws[i*3+2];
    float pcx = R00*pwx + R01*pwy + R02*pwz + t0;
    float pcy = R10*pwx + R11*pwy + R12*pwz + t1;
    float pcz = R20*pwx + R21*pwy + R22*pwz + t2;
    float depth = pcz;
    float zs = (depth > 0.2f) ? depth : 1.0f;
    float u0 = fx * pcx / zs + cx;
    float u1 = fy * pcy / zs + cy;

    float4 q4 = *reinterpret_cast<const float4*>(rots_raw + i*4);
    float qw=q4.x, qx=q4.y, qy=q4.z, qz=q4.w;
    float qn = sqrtf(qw*qw + qx*qx + qy*qy + qz*qz);
    qw/=qn; qx/=qn; qy/=qn; qz/=qn;
    float s0 = expf(scales_raw[i*3+0]);
    float s1 = expf(scales_raw[i*3+1]);
    float s2 = expf(scales_raw[i*3+2]);

    float xx=qx*qx, yy=qy*qy, zq=qz*qz;
    float xy=qx*qy, xz=qx*qz, yz=qy*qz;
    float wx=qw*qx, wy=qw*qy, wz=qw*qz;
    float r00=1.f-2.f*(yy+zq), r01=2.f*(xy-wz),     r02=2.f*(xz+wy);
    float r10=2.f*(xy+wz),     r11=1.f-2.f*(xx+zq), r12=2.f*(yz-wx);
    float r20=2.f*(xz-wy),     r21=2.f*(yz+wx),     r22=1.f-2.f*(xx+yy);

    float m00=r00*s0, m01=r01*s1, m02=r02*s2;
    float m10=r10*s0, m11=r11*s1, m12=r12*s2;
    float m20=r20*s0, m21=r21*s1, m22=r22*s2;
    float V00=m00*m00+m01*m01+m02*m02;
    float V01=m00*m10+m01*m11+m02*m12;
    float V02=m00*m20+m01*m21+m02*m22;
    float V11=m10*m10+m11*m11+m12*m12;
    float V12=m10*m20+m11*m21+m12*m22;
    float V22=m20*m20+m21*m21+m22*m22;

    float tanfx = (float)W / (2.f*fx), tanfy = (float)H / (2.f*fy);
    float limx = 1.3f*tanfx, limy = 1.3f*tanfy;
    float txl = fminf(fmaxf(pcx/zs, -limx), limx) * zs;
    float tyl = fminf(fmaxf(pcy/zs, -limy), limy) * zs;
    float iz = 1.f/zs, iz2 = iz*iz;
    float J00 = fx*iz, J02 = -fx*txl*iz2;
    float J11 = fy*iz, J12 = -fy*tyl*iz2;

    float T00=J00*R00+J02*R20, T01=J00*R01+J02*R21, T02=J00*R02+J02*R22;
    float T10=J11*R10+J12*R20, T11=J11*R11+J12*R21, T12=J11*R12+J12*R22;
    float A0=T00*V00+T01*V01+T02*V02;
    float A1=T00*V01+T01*V11+T02*V12;
    float A2=T00*V02+T01*V12+T02*V22;
    float B0=T10*V00+T11*V01+T12*V02;
    float B1=T10*V01+T11*V11+T12*V12;
    float B2=T10*V02+T11*V12+T12*V22;
    float ca = A0*T00+A1*T01+A2*T02 + 0.3f;
    float cb = A0*T10+A1*T11+A2*T12;
    float cc = B0*T10+B1*T11+B2*T12 + 0.3f;

    float det = ca*cc - cb*cb;
    bool valid = (depth > 0.2f) && (det > 0.f);
    float det_s = valid ? det : 1.f;
    float dinv = 1.f/det_s;
    float ci0 =  cc*dinv, ci1 = -cb*dinv, ci2 = ca*dinv;
    float mid = 0.5f*(ca+cc);
    float lam = mid + sqrtf(fmaxf(mid*mid - det, 0.1f));
    float radius = valid ? ceilf(3.f*sqrtf(lam)) : 0.f;
    areas[2*i+0] = radius;
    areas[2*i+1] = radius;

    float alpha = 1.f/(1.f + expf(-alphas_raw[i]));

    float tw0 = -(R00*t0 + R10*t1 + R20*t2);
    float tw1 = -(R01*t0 + R11*t1 + R21*t2);
    float tw2 = -(R02*t0 + R12*t1 + R22*t2);
    float dx_=pwx-tw0, dy_=pwy-tw1, dz_=pwz-tw2;
    float dn = sqrtf(dx_*dx_+dy_*dy_+dz_*dz_);
    float x=dx_/dn, y=dy_/dn, z=dz_/dn;
    float sxx=x*x, syy=y*y, szz=z*z;
    float sxy=x*y, syz=y*z, sxz=x*z;

    // 48 SH coeffs via 12 explicit float4 loads (base is 192B-aligned)
    float shl[48];
    const float4* sh4 = reinterpret_cast<const float4*>(shs + i*48);
    #pragma unroll
    for (int k = 0; k < 12; ++k) {
        float4 v = sh4[k];
        shl[4*k+0]=v.x; shl[4*k+1]=v.y; shl[4*k+2]=v.z; shl[4*k+3]=v.w;
    }
    float col[3];
    #pragma unroll
    for (int c = 0; c < 3; ++c) {
        float res = 0.28209479177387814f*shl[0*3+c];
        res += -0.4886025119029199f*y*shl[1*3+c]
             +  0.4886025119029199f*z*shl[2*3+c]
             + -0.4886025119029199f*x*shl[3*3+c];
        res +=  1.0925484305920792f*sxy*shl[4*3+c]
             + -1.0925484305920792f*syz*shl[5*3+c]
             +  0.31539156525252005f*(2.f*szz-sxx-syy)*shl[6*3+c]
             + -1.0925484305920792f*sxz*shl[7*3+c]
             +  0.5462742152960396f*(sxx-syy)*shl[8*3+c];
        res += -0.5900435899266435f*y*(3.f*sxx-syy)*shl[9*3+c]
             +  2.890611442640554f*sxy*z*shl[10*3+c]
             + -0.4570457994644658f*y*(4.f*szz-sxx-syy)*shl[11*3+c]
             +  0.3731763325901154f*z*(2.f*szz-3.f*sxx-3.f*syy)*shl[12*3+c]
             + -0.4570457994644658f*x*(4.f*szz-sxx-syy)*shl[13*3+c]
             +  1.445305721320277f*z*(sxx-syy)*shl[14*3+c]
             + -0.5900435899266435f*x*(sxx-3.f*syy)*shl[15*3+c];
        col[c] = fmaxf(res + 0.5f, 0.f);
    }

    float rc2;
    if (!valid || 255.f*alpha < 0.999f) {
        rc2 = -1.f;
    } else {
        float r2 = 2.f*lam*logf(255.f*alpha);
        float r  = sqrtf(fmaxf(r2, 0.f)) + 1.f;
        rc2 = r*r;
    }

    P[0*N+i]=u0;  P[1*N+i]=u1;  P[2*N+i]=ci0; P[3*N+i]=ci1; P[4*N+i]=ci2;
    P[5*N+i]=alpha; P[6*N+i]=col[0]; P[7*N+i]=col[1]; P[8*N+i]=col[2];
    P[9*N+i]=rc2;

    unsigned ud = __float_as_uint(depth);
    ud = (ud & 0x80000000u) ? ~ud : (ud | 0x80000000u);
    keys[i] = ((unsigned long long)ud << 32) | (unsigned)i;
}

// ---------------------------------------------------------------------------
// Kernel 2: O(N^2) rank sort fused with scatter. One i per thread.
// rank[i] accumulates (count | arrivals<<20) from the nJ j-tile blocks via
// one atomicAdd each (device-scope, G12). The block making the LAST arrival
// for i knows the final rank and scatters i's packed params:
//   cull[s] = (u0,u1,rc2,0); gA[s] = (ci0,ci1,ci2,alpha); gB[s] = (r,g,b,0)
// Fields can't interact: rank <= N-1 = 8191 < 2^20; arrivals <= 16.
// ---------------------------------------------------------------------------
#define JC 512
__global__ __launch_bounds__(256) void k_rank_scatter(
    const unsigned long long* __restrict__ keys, int N,
    unsigned* __restrict__ rank, const float* __restrict__ Pun,
    float4* __restrict__ gA, float4* __restrict__ gB,
    float4* __restrict__ cull)
{
    __shared__ unsigned long long sk[JC];
    const int j0 = blockIdx.y * JC;
    const int nJ = gridDim.y;
    for (int t = threadIdx.x; t < JC; t += 256) {
        int j = j0 + t;
        sk[t] = (j < N) ? keys[j] : ~0ull;
    }
    __syncthreads();

    const int i = blockIdx.x * 256 + threadIdx.x;
    unsigned long long my = (i < N) ? keys[i] : 0ull;

    int c = 0;
    const ulonglong2* sk2 = (const ulonglong2*)sk;
    #pragma unroll 4
    for (int t = 0; t < JC/2; ++t) {
        ulonglong2 kk = sk2[t];
        c += (kk.x < my) ? 1 : 0;
        c += (kk.y < my) ? 1 : 0;
    }
    if (i < N) {
        unsigned old = atomicAdd(&rank[i], (unsigned)c + (1u << 20));
        if ((int)(old >> 20) == nJ - 1) {
            int s = (int)(old & 0xFFFFFu) + c;
            cull[s] = make_float4(Pun[0*N+i], Pun[1*N+i], Pun[9*N+i], 0.f);
            gA[s]   = make_float4(Pun[2*N+i], Pun[3*N+i], Pun[4*N+i], Pun[5*N+i]);
            gB[s]   = make_float4(Pun[6*N+i], Pun[7*N+i], Pun[8*N+i], 0.f);
        }
    }
}

// ---------------------------------------------------------------------------
// Kernel 3: render. r5 structure (4 independent waves per block, each on one
// 8x8 tile of a 2x2 super-tile, same depth segment -> shared cull chunks in
// L1; 2048 blocks * 4 waves = 32 waves/CU) PLUS the r3 lesson applied where
// it can work: the per-chunk serial chain (cull load -> ballot -> DEPENDENT
// gA/gB load -> ds_write -> lgkmcnt -> ds_read) is replaced by
//   (a) 2-deep register prefetch of cull+gA+gB for chunk k+1 (unconditional),
//   (b) __shfl broadcast of the ~0-2 accepted splats' params from the owning
//       lane (iterate set bits of the ballot mask) -- zero LDS, no lgkmcnt
//       serialization, no dependent load after ballot.
// Per-chunk critical path ~100 cyc issue + residual load stall that 8
// waves/SIMD genuinely overlap. __launch_bounds__(256,8) pins <=64 VGPR.
// Local-T segmentation as rounds 0/1/4/5 (passed): C = C0 + T0*C1.
// ---------------------------------------------------------------------------
__global__ __launch_bounds__(256, 8) void k_render(
    const float4* __restrict__ gA, const float4* __restrict__ gB,
    const float4* __restrict__ cull, int N, int W, int H,
    int nSuper, int superX, int tilesX, int tilesY, int nseg,
    float4* __restrict__ segbuf)
{
    const int tid  = threadIdx.x;
    const int wv   = tid >> 6, lane = tid & 63;
    const int sup  = blockIdx.x % nSuper, seg = blockIdx.x / nSuper;
    const int sX   = sup % superX, sY = sup / superX;
    const int tX   = (sX << 1) + (wv & 1);
    const int tY   = (sY << 1) + (wv >> 1);
    const bool tOK = (tX < tilesX) && (tY < tilesY);
    const int ix = (tX << 3) + (lane & 7);
    const int iy = (tY << 3) + (lane >> 3);
    const bool inb = tOK && (ix < W) && (iy < H);
    const float pxf = (float)ix, pyf = (float)iy;
    const float tx0 = (float)(tX << 3), ty0 = (float)(tY << 3);
    int tx1i = (tX << 3) + 7; if (tx1i > W-1) tx1i = W-1;
    int ty1i = (tY << 3) + 7; if (ty1i > H-1) ty1i = H-1;
    const float tx1 = (float)tx1i, ty1 = (float)ty1i;

    const int per = (N + nseg - 1) / nseg;
    const int g0 = seg * per;
    const int g1 = min(N, g0 + per);

    float T = inb ? 1.f : 0.f;
    float aR = 0.f, aG = 0.f, aB = 0.f;

    if (tOK) {
        // prologue: chunk 0 into registers (clamped index is always a valid
        // address; acceptance is still gated on the true g < g1)
        int gl0 = min(g0 + lane, N - 1);
        float4 cu = cull[gl0];
        float4 a4 = gA[gl0];
        float4 b4 = gB[gl0];

        for (int base = g0; base < g1; base += 64) {
            // (a) unconditional prefetch of chunk k+1 (issued before any use
            // of chunk k's data; latency hides under this chunk's processing)
            float4 cu_n = make_float4(0.f, 0.f, -1.f, 0.f);
            float4 a4_n = make_float4(0.f, 0.f, 0.f, 0.f);
            float4 b4_n = make_float4(0.f, 0.f, 0.f, 0.f);
            if (base + 64 < g1) {
                int gln = min(base + 64 + lane, N - 1);
                cu_n = cull[gln];
                a4_n = gA[gln];
                b4_n = gB[gln];
            }

            // cull test on current chunk (all in regs)
            int g = base + lane;
            bool ov = false;
            if (g < g1) {
                float cxp = fminf(fmaxf(cu.x, tx0), tx1);
                float cyp = fminf(fmaxf(cu.y, ty0), ty1);
                float ddx = cu.x - cxp, ddy = cu.y - cyp;
                ov = (ddx*ddx + ddy*ddy) <= cu.z;
            }

            // (b) iterate accepted lanes in depth order, __shfl-broadcast
            unsigned long long mm = __ballot(ov);
            while (mm) {
                int l = __ffsll(mm) - 1;
                mm &= mm - 1ull;
                float su0 = __shfl(cu.x, l), su1 = __shfl(cu.y, l);
                float ci0 = __shfl(a4.x, l), ci1 = __shfl(a4.y, l);
                float ci2 = __shfl(a4.z, l), sal = __shfl(a4.w, l);
                float cr  = __shfl(b4.x, l), cg  = __shfl(b4.y, l);
                float cbv = __shfl(b4.z, l);
                float ddx = pxf - su0, ddy = pyf - su1;
                float power = -0.5f*(ci0*ddx*ddx + ci2*ddy*ddy) - ci1*ddx*ddy;
                float alp = fminf(0.99f, sal * __expf(power));
                alp = (power <= 0.f && alp >= (1.0f/255.0f)) ? alp : 0.f;
                float w = (T > 0.0001f) ? alp * T : 0.f;
                aR = fmaf(w, cr, aR);
                aG = fmaf(w, cg, aG);
                aB = fmaf(w, cbv, aB);
                T = T - T * alp;
            }
            if (__all(T <= 0.0001f)) break;
            cu = cu_n; a4 = a4_n; b4 = b4_n;
        }
    }

    if (inb) {
        int pix = iy * W + ix;
        segbuf[(size_t)seg * (size_t)(W*H) + pix] = make_float4(T, aR, aG, aB);
    }
}

// ---------------------------------------------------------------------------
// Kernel 4: combine depth segments front-to-back.
// ---------------------------------------------------------------------------
__global__ __launch_bounds__(256) void k_combine(
    const float4* __restrict__ segbuf, int HW, int nseg,
    float* __restrict__ out)
{
    int p = blockIdx.x * 256 + threadIdx.x;
    if (p >= HW) return;
    float T = 1.f, r = 0.f, g = 0.f, b = 0.f;
    for (int s = 0; s < nseg; ++s) {
        float4 v = segbuf[(size_t)s * HW + p];
        r = fmaf(T, v.y, r);
        g = fmaf(T, v.z, g);
        b = fmaf(T, v.w, b);
        T *= v.x;
    }
    out[p] = r; out[HW + p] = g; out[2*HW + p] = b;
}

// ---------------------------------------------------------------------------
extern "C" void kernel_launch(void* const* d_in, const int* in_sizes, int n_in,
                              void* d_out, int out_size, void* d_ws, size_t ws_size,
                              hipStream_t stream) {
    const float* pws        = (const float*)d_in[0];
    const float* shs        = (const float*)d_in[1];
    const float* alphas_raw = (const float*)d_in[2];
    const float* scales_raw = (const float*)d_in[3];
    const float* rots_raw   = (const float*)d_in[4];
    // d_in[5] = us (forward value cancels: u + us - us)
    const float* Rcw        = (const float*)d_in[6];
    const float* tcw        = (const float*)d_in[7];
    const float* intr       = (const float*)d_in[8];

    const int N  = in_sizes[0] / 3;
    const int HW = (out_size - 2 * N) / 3;
    int W = 1; while ((long long)W * W < (long long)HW) ++W;  // square image
    const int H = HW / W;

    float* out   = (float*)d_out;
    float* areas = out + 3 * HW;

    // workspace carve-up (16B-aligned pieces)
    char* ws = (char*)d_ws;
    size_t off = 0;
    unsigned long long* keys = (unsigned long long*)(ws + off); off += (size_t)N * 8;
    unsigned* rank = (unsigned*)(ws + off);                     off += (size_t)N * 4;
    off = (off + 15) & ~(size_t)15;
    float* Pun = (float*)(ws + off);                            off += (size_t)10 * N * 4;
    off = (off + 15) & ~(size_t)15;
    float4* cullv = (float4*)(ws + off);                        off += (size_t)N * 16;
    float4* gA = (float4*)(ws + off);                           off += (size_t)N * 16;
    float4* gB = (float4*)(ws + off);                           off += (size_t)N * 16;
    float4* segbuf = (float4*)(ws + off);
    size_t remain = (ws_size > off) ? (ws_size - off) : 0;
    int nseg = 8;
    while (nseg > 1 && (size_t)nseg * (size_t)HW * 16 > remain) nseg >>= 1;

    k_pre<<<(N + 63) / 64, 64, 0, stream>>>(pws, shs, alphas_raw, scales_raw,
                                            rots_raw, Rcw, tcw, intr, N, W, H,
                                            areas, keys, rank, Pun);
    dim3 rgrid((N + 255) / 256, (N + JC - 1) / JC);
    k_rank_scatter<<<rgrid, 256, 0, stream>>>(keys, N, rank, Pun, gA, gB, cullv);
    int tilesX = (W + 7) / 8, tilesY = (H + 7) / 8;
    int superX = (tilesX + 1) / 2, superY = (tilesY + 1) / 2;
    int nSuper = superX * superY;
    k_render<<<nSuper * nseg, 256, 0, stream>>>(gA, gB, cullv, N, W, H,
                                                nSuper, superX, tilesX, tilesY,
                                                nseg, segbuf);
    k_combine<<<(HW + 255) / 256, 256, 0, stream>>>(segbuf, HW, nseg, out);
}